// Round 5
// baseline (46.391 us; speedup 1.0000x reference)
//
#include <hip/hip_runtime.h>

// DistortionLoss: per-ray exclusive scan of ws and ws*ts, loss accumulate, global mean.
// ONE ray per 16-lane group (4 rays/wave). 16 elems/lane, 12 upfront float4 loads.
// Local contribution folded into 5 running accumulators (C1,C2,pw,pt,uni); only the
// lane totals (pw,pt) cross the 4-step group scan:
//   loss_local = 2*(ex*ptTot + C1 - ext*pwTot - C2) + uni
// w-only masking annihilates out-of-ray garbage. Stage1 -> partials; Stage2 -> scalar.

__device__ __forceinline__ float ray_loss_chunked(
    const float* __restrict__ ws, const float* __restrict__ deltas,
    const float* __restrict__ ts, int start, int count, int N, int lane)
{
    const int abase = start & ~3;
    const int lo    = start - abase;
    const int hi    = lo + count;
    float loss = 0.f, carry_w = 0.f, carry_wt = 0.f;
    for (int base = 0; base < hi; base += 256) {
        const int i0 = base + 4 * lane;
        float4 w4 = make_float4(0.f,0.f,0.f,0.f), t4 = w4, d4 = w4;
        if (i0 < hi && abase + i0 < N) {
            w4 = *reinterpret_cast<const float4*>(ws     + abase + i0);
            t4 = *reinterpret_cast<const float4*>(ts     + abase + i0);
            d4 = *reinterpret_cast<const float4*>(deltas + abase + i0);
        }
        const unsigned uc = (unsigned)count;
        const float w0 = ((unsigned)(i0 + 0 - lo) < uc) ? w4.x : 0.f;
        const float w1 = ((unsigned)(i0 + 1 - lo) < uc) ? w4.y : 0.f;
        const float w2 = ((unsigned)(i0 + 2 - lo) < uc) ? w4.z : 0.f;
        const float w3 = ((unsigned)(i0 + 3 - lo) < uc) ? w4.w : 0.f;
        const float wt0 = w0*t4.x, wt1 = w1*t4.y, wt2 = w2*t4.z, wt3 = w3*t4.w;
        const float pw0 = w0,       pwt0 = wt0;
        const float pw1 = pw0 + w1, pwt1 = pwt0 + wt1;
        const float pw2 = pw1 + w2, pwt2 = pwt1 + wt2;
        const float pw3 = pw2 + w3, pwt3 = pwt2 + wt3;
        float sw = pw3, swt = pwt3;
        #pragma unroll
        for (int off = 1; off < 64; off <<= 1) {
            const float aw  = __shfl_up(sw,  off);
            const float awt = __shfl_up(swt, off);
            if (lane >= off) { sw += aw; swt += awt; }
        }
        const float exw  = carry_w  + (sw  - pw3);
        const float exwt = carry_wt + (swt - pwt3);
        const float W0 = exw,       WT0 = exwt;
        const float W1 = exw + pw0, WT1 = exwt + pwt0;
        const float W2 = exw + pw1, WT2 = exwt + pwt1;
        const float W3 = exw + pw2, WT3 = exwt + pwt2;
        loss += 2.f * (w0*(t4.x*W0 - WT0) + w1*(t4.y*W1 - WT1)
                     + w2*(t4.z*W2 - WT2) + w3*(t4.w*W3 - WT3))
              + (w0*w0*d4.x + w1*w1*d4.y + w2*w2*d4.z + w3*w3*d4.w) * (1.f/3.f);
        carry_w  += __shfl(sw,  63);
        carry_wt += __shfl(swt, 63);
    }
    return loss;
}

__global__ __launch_bounds__(256) void distloss_stage1(
    const float* __restrict__ ws,
    const float* __restrict__ deltas,
    const float* __restrict__ ts,
    const int*   __restrict__ rays_a,
    float*       __restrict__ partial,
    int N)
{
    const int lane = threadIdx.x & 63;
    const int li   = lane & 15;                      // index within 16-lane group
    const int wid  = (blockIdx.x * blockDim.x + threadIdx.x) >> 6;
    const int ray  = 4 * wid + (lane >> 4);          // 4 rays per wave

    const int start = rays_a[ray * 3 + 1];
    const int count = rays_a[ray * 3 + 2];
    const int abase = start & ~3;                    // 16B-aligned window base
    const int lo    = start - abase;                 // 0..3
    const int hi    = lo + count;                    // window extent (<=199 real data)

    float loss = 0.f;

    if (!__any(hi > 256)) {
        // ---- fast path: ray fits the 256-elem window of its 16-lane group ----
        const int i0 = 16 * li;
        const int g  = abase + i0;
        const float4 z = make_float4(0.f, 0.f, 0.f, 0.f);
        float4 W4[4] = {z,z,z,z}, T4[4] = {z,z,z,z}, D4[4] = {z,z,z,z};
        // 12 independent predicated loads, issued upfront (aligned quads: first
        // elem < N and N%4==0 => whole quad in bounds)
        #pragma unroll
        for (int q = 0; q < 4; ++q) {
            if (i0 + 4*q < hi) {
                W4[q] = *reinterpret_cast<const float4*>(ws     + g + 4*q);
                T4[q] = *reinterpret_cast<const float4*>(ts     + g + 4*q);
                D4[q] = *reinterpret_cast<const float4*>(deltas + g + 4*q);
            }
        }

        const float* Wf = reinterpret_cast<const float*>(W4);
        const float* Tf = reinterpret_cast<const float*>(T4);
        const float* Df = reinterpret_cast<const float*>(D4);

        // local accumulation: 4 interleaved FMA chains, fully unrolled (static idx)
        float pw = 0.f, pt = 0.f, C1 = 0.f, C2 = 0.f, uni = 0.f;
        const unsigned uc = (unsigned)count;
        #pragma unroll
        for (int k = 0; k < 16; ++k) {
            const float w  = ((unsigned)(i0 + k - lo) < uc) ? Wf[k] : 0.f;
            const float t  = Tf[k];
            const float d  = Df[k];
            const float wt = w * t;
            C1  += wt * pw;          // wt_k * (local excl prefix of w)
            C2  += w  * pt;          // w_k  * (local excl prefix of wt)
            pw  += w;
            pt  += wt;
            uni += w * w * d;
        }

        // 4-step inclusive scan of lane totals across the 16-lane group
        float sw = pw, st = pt;
        #pragma unroll
        for (int off = 1; off < 16; off <<= 1) {
            const float aw = __shfl_up(sw, off);
            const float at = __shfl_up(st, off);
            if (li >= off) { sw += aw; st += at; }
        }
        const float ex  = sw - pw;                   // exclusive lane prefix of w
        const float ext = st - pt;                   // exclusive lane prefix of wt

        loss = 2.f * (ex * pt + C1 - ext * pw - C2) + uni * (1.f / 3.f);
    } else {
        // ---- rare fallback: full-wave chunked scan, one ray at a time ----
        #pragma unroll
        for (int r = 0; r < 4; ++r) {
            const int s = __shfl(start, 16 * r);
            const int c = __shfl(count, 16 * r);
            loss += ray_loss_chunked(ws, deltas, ts, s, c, N, lane);
        }
    }

    // wave reduction (sums all 4 rays of the wave)
    #pragma unroll
    for (int off = 32; off > 0; off >>= 1) loss += __shfl_xor(loss, off);

    __shared__ float sacc[4];
    if (lane == 0) sacc[threadIdx.x >> 6] = loss;
    __syncthreads();
    if (threadIdx.x == 0)
        partial[blockIdx.x] = (sacc[0] + sacc[1]) + (sacc[2] + sacc[3]);
}

__global__ __launch_bounds__(1024) void distloss_stage2(
    const float* __restrict__ partial,
    float*       __restrict__ out,
    int n, float inv_R)
{
    float s = 0.f;
    for (int i = threadIdx.x; i < n; i += 1024) s += partial[i];

    #pragma unroll
    for (int off = 32; off > 0; off >>= 1) s += __shfl_xor(s, off);

    __shared__ float sacc[16];
    const int lane = threadIdx.x & 63;
    if (lane == 0) sacc[threadIdx.x >> 6] = s;
    __syncthreads();
    if (threadIdx.x == 0) {
        float tot = 0.f;
        #pragma unroll
        for (int k = 0; k < 16; ++k) tot += sacc[k];
        out[0] = tot * inv_R;
    }
}

extern "C" void kernel_launch(void* const* d_in, const int* in_sizes, int n_in,
                              void* d_out, int out_size, void* d_ws, size_t ws_size,
                              hipStream_t stream) {
    const float* ws     = (const float*)d_in[0];
    const float* deltas = (const float*)d_in[1];
    const float* ts     = (const float*)d_in[2];
    const int*   rays_a = (const int*)d_in[3];
    float* out     = (float*)d_out;
    float* partial = (float*)d_ws;

    const int N = in_sizes[0];              // 8388608 samples
    const int R = in_sizes[3] / 3;          // 65536 rays
    const int blocks = R / 16;              // 4 rays/wave, 4 waves/block

    distloss_stage1<<<blocks, 256, 0, stream>>>(ws, deltas, ts, rays_a, partial, N);
    distloss_stage2<<<1, 1024, 0, stream>>>(partial, out, blocks, 1.0f / (float)R);
}